// Round 1
// baseline (6407.907 us; speedup 1.0000x reference)
//
#include <hip/hip_runtime.h>

#define NN 100000      // N_NODES
#define NE 1000000     // N_EDGES
#define HID 75
#define SP 80          // padded feature stride (floats)
#define CH 20          // float4 chunks per padded row
#define OUTF 64
#define CH64 16
#define BN_EPS 1e-5f

// ---------------- degree / dinv ----------------
__global__ void deg_count(const int* __restrict__ dst, float* __restrict__ deg, int E) {
    int e = blockIdx.x * blockDim.x + threadIdx.x;
    if (e < E) atomicAdd(&deg[dst[e]], 1.0f);
}

__global__ void dinv_kernel(float* __restrict__ deg, int n) {
    int i = blockIdx.x * blockDim.x + threadIdx.x;
    if (i < n) deg[i] = rsqrtf(deg[i] + 1.0f);   // +1 for self-loop
}

// ---------------- embedding gather ----------------
__global__ void embed_kernel(const int* __restrict__ x, const float* __restrict__ emb,
                             float* __restrict__ h) {
    int t = blockIdx.x * blockDim.x + threadIdx.x;
    if (t >= NN * SP) return;
    int node = t / SP, f = t % SP;
    h[t] = (f < HID) ? emb[x[node] * HID + f] : 0.0f;
}

// ---------------- GEMM: out[n][0..J) = h[n][0..75) @ W (75 x J) ----------------
// h has stride SP. J==75 -> out stride SP (pad chunk zeroed). J==64 -> stride 64.
template<int J>
__global__ void gemm_kernel(const float* __restrict__ h, const float* __restrict__ W,
                            float* __restrict__ out) {
    constexpr int CJ = (J + 3) / 4;   // 19 or 16
    constexpr int JP = CJ * 4;        // 76 or 64
    constexpr int NB = 256 / CJ;      // 13 or 16
    __shared__ float Wlds[HID * JP];
    for (int idx = threadIdx.x; idx < HID * JP; idx += 256) {
        int k = idx / JP, j = idx % JP;
        Wlds[idx] = (j < J) ? W[k * J + j] : 0.0f;
    }
    __syncthreads();
    int nn_local = threadIdx.x / CJ;
    int c = threadIdx.x % CJ;
    if (nn_local >= NB) return;
    int n = blockIdx.x * NB + nn_local;
    if (n >= NN) return;
    const float* hrow = h + (size_t)n * SP;
    float4 acc = make_float4(0.f, 0.f, 0.f, 0.f);
    #pragma unroll 5
    for (int k = 0; k < HID; ++k) {
        float hk = hrow[k];
        float4 w4 = *reinterpret_cast<const float4*>(&Wlds[k * JP + c * 4]);
        acc.x = fmaf(hk, w4.x, acc.x);
        acc.y = fmaf(hk, w4.y, acc.y);
        acc.z = fmaf(hk, w4.z, acc.z);
        acc.w = fmaf(hk, w4.w, acc.w);
    }
    if (J == HID) {
        float4* o = reinterpret_cast<float4*>(out + (size_t)n * SP);
        o[c] = acc;
        if (c == 0) o[CH - 1] = make_float4(0.f, 0.f, 0.f, 0.f);  // zero pad chunk
    } else {
        float4* o = reinterpret_cast<float4*>(out + (size_t)n * J);
        o[c] = acc;
    }
}

// ---------------- aggregation: self-loop init + edge scatter ----------------
__global__ void self_init75(const float* __restrict__ hW, const float* __restrict__ dinv,
                            float* __restrict__ agg) {
    int t = blockIdx.x * blockDim.x + threadIdx.x;
    if (t >= NN * CH) return;
    int n = t / CH;
    float d = dinv[n];
    float s = d * d;
    float4 v = reinterpret_cast<const float4*>(hW)[t];
    reinterpret_cast<float4*>(agg)[t] = make_float4(v.x * s, v.y * s, v.z * s, v.w * s);
}

__global__ void scatter75(const int* __restrict__ src, const int* __restrict__ dst,
                          const float* __restrict__ hW, const float* __restrict__ dinv,
                          float* __restrict__ agg, int E) {
    int t = blockIdx.x * blockDim.x + threadIdx.x;
    if (t >= E * CH) return;
    int e = t / CH, c = t % CH;
    int s = src[e], d = dst[e];
    float norm = dinv[s] * dinv[d];
    float4 v = reinterpret_cast<const float4*>(hW + (size_t)s * SP)[c];
    float* o = agg + (size_t)d * SP + c * 4;
    atomicAdd(o + 0, v.x * norm);
    atomicAdd(o + 1, v.y * norm);
    atomicAdd(o + 2, v.z * norm);
    atomicAdd(o + 3, v.w * norm);
}

// ---------------- BN stats: column sum & sumsq ----------------
__global__ void stats_kernel(const float* __restrict__ agg, float* __restrict__ stats) {
    __shared__ float ssum[SP], ssq[SP];
    if (threadIdx.x < SP) { ssum[threadIdx.x] = 0.f; ssq[threadIdx.x] = 0.f; }
    __syncthreads();
    int gtid = blockIdx.x * blockDim.x + threadIdx.x;
    int T = gridDim.x * blockDim.x;          // must be divisible by CH
    int c = gtid % CH;
    int r = gtid / CH;
    int rstep = T / CH;
    float4 s = make_float4(0.f, 0.f, 0.f, 0.f), q = make_float4(0.f, 0.f, 0.f, 0.f);
    for (; r < NN; r += rstep) {
        float4 v = reinterpret_cast<const float4*>(agg)[r * CH + c];
        s.x += v.x; s.y += v.y; s.z += v.z; s.w += v.w;
        q.x += v.x * v.x; q.y += v.y * v.y; q.z += v.z * v.z; q.w += v.w * v.w;
    }
    atomicAdd(&ssum[c * 4 + 0], s.x); atomicAdd(&ssum[c * 4 + 1], s.y);
    atomicAdd(&ssum[c * 4 + 2], s.z); atomicAdd(&ssum[c * 4 + 3], s.w);
    atomicAdd(&ssq[c * 4 + 0], q.x); atomicAdd(&ssq[c * 4 + 1], q.y);
    atomicAdd(&ssq[c * 4 + 2], q.z); atomicAdd(&ssq[c * 4 + 3], q.w);
    __syncthreads();
    if (threadIdx.x < SP) {
        atomicAdd(&stats[threadIdx.x], ssum[threadIdx.x]);
        atomicAdd(&stats[SP + threadIdx.x], ssq[threadIdx.x]);
    }
}

// stats -> affine (a, c): y = x*a + c   (GCN bias cancels in BN)
__global__ void bn_finalize(const float* __restrict__ stats, const float* __restrict__ gamma,
                            const float* __restrict__ beta, float* __restrict__ ab) {
    int f = threadIdx.x;
    if (f >= SP) return;
    float a = 0.f, cc = 0.f;
    if (f < HID) {
        float mu = stats[f] * (1.0f / NN);
        float var = stats[SP + f] * (1.0f / NN) - mu * mu;
        a = gamma[f] * rsqrtf(var + BN_EPS);
        cc = beta[f] - mu * a;
    }
    ab[f] = a;
    ab[SP + f] = cc;
}

__global__ void bn_relu(float* __restrict__ h, const float* __restrict__ ab) {
    int t = blockIdx.x * blockDim.x + threadIdx.x;
    if (t >= NN * CH) return;
    int c = t % CH;
    float4 v = reinterpret_cast<float4*>(h)[t];
    float4 a = reinterpret_cast<const float4*>(ab)[c];
    float4 b = reinterpret_cast<const float4*>(ab + SP)[c];
    v.x = fmaxf(fmaf(v.x, a.x, b.x), 0.f);
    v.y = fmaxf(fmaf(v.y, a.y, b.y), 0.f);
    v.z = fmaxf(fmaf(v.z, a.z, b.z), 0.f);
    v.w = fmaxf(fmaf(v.w, a.w, b.w), 0.f);
    reinterpret_cast<float4*>(h)[t] = v;
}

// ---------------- final convs (stride 64, with bias) ----------------
__global__ void out_init64(const float* __restrict__ hW, const float* __restrict__ dinv,
                           const float* __restrict__ bias, float* __restrict__ out) {
    int t = blockIdx.x * blockDim.x + threadIdx.x;
    if (t >= NN * CH64) return;
    int n = t / CH64, c = t % CH64;
    float d = dinv[n];
    float s = d * d;
    float4 v = reinterpret_cast<const float4*>(hW)[t];
    float4 b = reinterpret_cast<const float4*>(bias)[c];
    reinterpret_cast<float4*>(out)[t] =
        make_float4(fmaf(v.x, s, b.x), fmaf(v.y, s, b.y), fmaf(v.z, s, b.z), fmaf(v.w, s, b.w));
}

__global__ void scatter64(const int* __restrict__ src, const int* __restrict__ dst,
                          const float* __restrict__ hW, const float* __restrict__ dinv,
                          float* __restrict__ out, int E) {
    int t = blockIdx.x * blockDim.x + threadIdx.x;
    if (t >= E * CH64) return;
    int e = t / CH64, c = t % CH64;
    int s = src[e], d = dst[e];
    float norm = dinv[s] * dinv[d];
    float4 v = reinterpret_cast<const float4*>(hW + (size_t)s * OUTF)[c];
    float* o = out + (size_t)d * OUTF + c * 4;
    atomicAdd(o + 0, v.x * norm);
    atomicAdd(o + 1, v.y * norm);
    atomicAdd(o + 2, v.z * norm);
    atomicAdd(o + 3, v.w * norm);
}

// ---------------- host ----------------
extern "C" void kernel_launch(void* const* d_in, const int* in_sizes, int n_in,
                              void* d_out, int out_size, void* d_ws, size_t ws_size,
                              hipStream_t stream) {
    const int*   x      = (const int*)d_in[0];
    const int*   ei     = (const int*)d_in[1];
    const float* emb    = (const float*)d_in[2];
    const float* Ws     = (const float*)d_in[3];
    const float* gammas = (const float*)d_in[5];
    const float* betas  = (const float*)d_in[6];
    const float* W_mu   = (const float*)d_in[7];
    const float* b_mu   = (const float*)d_in[8];
    const float* W_ls   = (const float*)d_in[9];
    const float* b_ls   = (const float*)d_in[10];
    float* out = (float*)d_out;

    const int E = in_sizes[1] / 2;
    const int* src = ei;
    const int* dst = ei + E;

    char* ws = (char*)d_ws;
    float* dinv  = (float*)(ws + 0);          // NN floats
    float* stats = (float*)(ws + 400000);     // 160 floats (sum, sumsq)
    float* ab    = (float*)(ws + 400640);     // 160 floats (a, c)
    float* hA    = (float*)(ws + 401408);     // NN*SP floats  (current h)
    float* hB    = (float*)(ws + 32401408);   // NN*SP floats  (hW scratch)

    // degrees -> dinv
    hipMemsetAsync(dinv, 0, NN * sizeof(float), stream);
    deg_count<<<(E + 255) / 256, 256, 0, stream>>>(dst, dinv, E);
    dinv_kernel<<<(NN + 255) / 256, 256, 0, stream>>>(dinv, NN);

    // h0 = emb[x]
    embed_kernel<<<(NN * SP + 255) / 256, 256, 0, stream>>>(x, emb, hA);

    for (int layer = 0; layer < 4; ++layer) {
        const float* W = Ws + (size_t)layer * HID * HID;
        gemm_kernel<HID><<<(NN + 12) / 13, 256, 0, stream>>>(hA, W, hB);
        self_init75<<<(NN * CH + 255) / 256, 256, 0, stream>>>(hB, dinv, hA);
        scatter75<<<(NE * CH + 255) / 256, 256, 0, stream>>>(src, dst, hB, dinv, hA, E);
        hipMemsetAsync(stats, 0, 2 * SP * sizeof(float), stream);
        stats_kernel<<<640, 256, 0, stream>>>(hA, stats);
        bn_finalize<<<1, 128, 0, stream>>>(stats, gammas + layer * HID, betas + layer * HID, ab);
        bn_relu<<<(NN * CH + 255) / 256, 256, 0, stream>>>(hA, ab);
    }

    // mu
    gemm_kernel<OUTF><<<(NN + 15) / 16, 256, 0, stream>>>(hA, W_mu, hB);
    out_init64<<<(NN * CH64 + 255) / 256, 256, 0, stream>>>(hB, dinv, b_mu, out);
    scatter64<<<(NE * CH64 + 255) / 256, 256, 0, stream>>>(src, dst, hB, dinv, out, E);

    // logstd
    float* out2 = out + (size_t)NN * OUTF;
    gemm_kernel<OUTF><<<(NN + 15) / 16, 256, 0, stream>>>(hA, W_ls, hB);
    out_init64<<<(NN * CH64 + 255) / 256, 256, 0, stream>>>(hB, dinv, b_ls, out2);
    scatter64<<<(NE * CH64 + 255) / 256, 256, 0, stream>>>(src, dst, hB, dinv, out2, E);
}

// Round 2
// 894.050 us; speedup vs baseline: 7.1673x; 7.1673x over previous
//
#include <hip/hip_runtime.h>

#define NN 100000      // N_NODES
#define NE 1000000     // N_EDGES
#define HID 75
#define SP 80          // padded feature stride (floats)
#define CH 20          // float4 chunks per padded row
#define OUTF 64
#define CH64 16
#define BN_EPS 1e-5f

#define SCAN_ELEMS 1024
#define SCAN_NBLK ((NN + SCAN_ELEMS - 1) / SCAN_ELEMS)   // 98

// ---------------- CSR build ----------------
__global__ void hist_kernel(const int* __restrict__ dst, int* __restrict__ hist, int E) {
    int e = blockIdx.x * blockDim.x + threadIdx.x;
    if (e < E) atomicAdd(&hist[dst[e]], 1);
}

__global__ void dinv_kernel(const int* __restrict__ hist, float* __restrict__ dinv, int n) {
    int i = blockIdx.x * blockDim.x + threadIdx.x;
    if (i < n) dinv[i] = rsqrtf((float)hist[i] + 1.0f);   // +1 self-loop
}

__global__ void scan_pass1(const int* __restrict__ hist, int* __restrict__ bsum) {
    __shared__ int sdata[256];
    int base = blockIdx.x * SCAN_ELEMS;
    int t = threadIdx.x;
    int s = 0;
    #pragma unroll
    for (int k = 0; k < 4; ++k) {
        int i = base + t * 4 + k;
        if (i < NN) s += hist[i];
    }
    sdata[t] = s;
    __syncthreads();
    for (int off = 128; off > 0; off >>= 1) {
        if (t < off) sdata[t] += sdata[t + off];
        __syncthreads();
    }
    if (t == 0) bsum[blockIdx.x] = sdata[0];
}

__global__ void scan_pass2(int* __restrict__ bsum, int* __restrict__ row_ptr, int nblk) {
    if (threadIdx.x == 0) {
        int acc = 0;
        for (int i = 0; i < nblk; ++i) { int v = bsum[i]; bsum[i] = acc; acc += v; }
        row_ptr[NN] = acc;
    }
}

__global__ void scan_pass3(const int* __restrict__ hist, const int* __restrict__ bsum,
                           int* __restrict__ row_ptr) {
    __shared__ int sdata[256];
    int base = blockIdx.x * SCAN_ELEMS;
    int t = threadIdx.x;
    int v[4];
    int s = 0;
    #pragma unroll
    for (int k = 0; k < 4; ++k) {
        int i = base + t * 4 + k;
        v[k] = (i < NN) ? hist[i] : 0;
        s += v[k];
    }
    sdata[t] = s;
    __syncthreads();
    for (int off = 1; off < 256; off <<= 1) {
        int x = (t >= off) ? sdata[t - off] : 0;
        __syncthreads();
        sdata[t] += x;
        __syncthreads();
    }
    int pre = bsum[blockIdx.x] + sdata[t] - s;   // exclusive offset for this thread
    #pragma unroll
    for (int k = 0; k < 4; ++k) {
        int i = base + t * 4 + k;
        if (i < NN) { row_ptr[i] = pre; pre += v[k]; }
    }
}

__global__ void csr_fill(const int* __restrict__ src, const int* __restrict__ dst,
                         const int* __restrict__ row_ptr, int* __restrict__ cnt,
                         const float* __restrict__ dinv, int* __restrict__ col,
                         float* __restrict__ wgt, int E) {
    int e = blockIdx.x * blockDim.x + threadIdx.x;
    if (e >= E) return;
    int s = src[e], d = dst[e];
    int slot = row_ptr[d] + atomicAdd(&cnt[d], 1);
    col[slot] = s;
    wgt[slot] = dinv[s] * dinv[d];
}

// ---------------- embedding gather ----------------
__global__ void embed_kernel(const int* __restrict__ x, const float* __restrict__ emb,
                             float* __restrict__ h) {
    int t = blockIdx.x * blockDim.x + threadIdx.x;
    if (t >= NN * SP) return;
    int node = t / SP, f = t % SP;
    h[t] = (f < HID) ? emb[x[node] * HID + f] : 0.0f;
}

// ---------------- GEMM: out[n][0..J) = h[n][0..75) @ W (75 x J) ----------------
template<int J>
__global__ void gemm_kernel(const float* __restrict__ h, const float* __restrict__ W,
                            float* __restrict__ out) {
    constexpr int CJ = (J + 3) / 4;   // 19 or 16
    constexpr int JP = CJ * 4;        // 76 or 64
    constexpr int NB = 256 / CJ;      // 13 or 16
    __shared__ float Wlds[HID * JP];
    for (int idx = threadIdx.x; idx < HID * JP; idx += 256) {
        int k = idx / JP, j = idx % JP;
        Wlds[idx] = (j < J) ? W[k * J + j] : 0.0f;
    }
    __syncthreads();
    int nn_local = threadIdx.x / CJ;
    int c = threadIdx.x % CJ;
    if (nn_local >= NB) return;
    int n = blockIdx.x * NB + nn_local;
    if (n >= NN) return;
    const float* hrow = h + (size_t)n * SP;
    float4 acc = make_float4(0.f, 0.f, 0.f, 0.f);
    #pragma unroll 5
    for (int k = 0; k < HID; ++k) {
        float hk = hrow[k];
        float4 w4 = *reinterpret_cast<const float4*>(&Wlds[k * JP + c * 4]);
        acc.x = fmaf(hk, w4.x, acc.x);
        acc.y = fmaf(hk, w4.y, acc.y);
        acc.z = fmaf(hk, w4.z, acc.z);
        acc.w = fmaf(hk, w4.w, acc.w);
    }
    if (J == HID) {
        float4* o = reinterpret_cast<float4*>(out + (size_t)n * SP);
        o[c] = acc;
        if (c == 0) o[CH - 1] = make_float4(0.f, 0.f, 0.f, 0.f);  // zero pad chunk
    } else {
        float4* o = reinterpret_cast<float4*>(out + (size_t)n * J);
        o[c] = acc;
    }
}

// ---------------- CSR gather aggregation ----------------
__global__ void gather75(const int* __restrict__ row_ptr, const int* __restrict__ col,
                         const float* __restrict__ wgt, const float* __restrict__ hW,
                         const float* __restrict__ dinv, float* __restrict__ agg) {
    int t = blockIdx.x * blockDim.x + threadIdx.x;
    if (t >= NN * CH) return;
    int n = t / CH, c = t % CH;
    int beg = row_ptr[n], end = row_ptr[n + 1];
    float dn = dinv[n];
    float s2 = dn * dn;
    const float4* h4 = reinterpret_cast<const float4*>(hW);
    float4 acc = h4[n * CH + c];
    acc.x *= s2; acc.y *= s2; acc.z *= s2; acc.w *= s2;
    for (int e = beg; e < end; ++e) {
        int s = col[e];
        float wt = wgt[e];
        float4 v = h4[s * CH + c];
        acc.x = fmaf(v.x, wt, acc.x);
        acc.y = fmaf(v.y, wt, acc.y);
        acc.z = fmaf(v.z, wt, acc.z);
        acc.w = fmaf(v.w, wt, acc.w);
    }
    reinterpret_cast<float4*>(agg)[t] = acc;
}

__global__ void gather64(const int* __restrict__ row_ptr, const int* __restrict__ col,
                         const float* __restrict__ wgt, const float* __restrict__ hW,
                         const float* __restrict__ dinv, const float* __restrict__ bias,
                         float* __restrict__ out) {
    int t = blockIdx.x * blockDim.x + threadIdx.x;
    if (t >= NN * CH64) return;
    int n = t / CH64, c = t % CH64;
    int beg = row_ptr[n], end = row_ptr[n + 1];
    float dn = dinv[n];
    float s2 = dn * dn;
    const float4* h4 = reinterpret_cast<const float4*>(hW);
    float4 b = reinterpret_cast<const float4*>(bias)[c];
    float4 acc = h4[n * CH64 + c];
    acc.x = fmaf(acc.x, s2, b.x);
    acc.y = fmaf(acc.y, s2, b.y);
    acc.z = fmaf(acc.z, s2, b.z);
    acc.w = fmaf(acc.w, s2, b.w);
    for (int e = beg; e < end; ++e) {
        int s = col[e];
        float wt = wgt[e];
        float4 v = h4[s * CH64 + c];
        acc.x = fmaf(v.x, wt, acc.x);
        acc.y = fmaf(v.y, wt, acc.y);
        acc.z = fmaf(v.z, wt, acc.z);
        acc.w = fmaf(v.w, wt, acc.w);
    }
    reinterpret_cast<float4*>(out)[t] = acc;
}

// ---------------- BN stats: column sum & sumsq ----------------
__global__ void stats_kernel(const float* __restrict__ agg, float* __restrict__ stats) {
    __shared__ float ssum[SP], ssq[SP];
    if (threadIdx.x < SP) { ssum[threadIdx.x] = 0.f; ssq[threadIdx.x] = 0.f; }
    __syncthreads();
    int gtid = blockIdx.x * blockDim.x + threadIdx.x;
    int T = gridDim.x * blockDim.x;          // divisible by CH
    int c = gtid % CH;
    int r = gtid / CH;
    int rstep = T / CH;
    float4 s = make_float4(0.f, 0.f, 0.f, 0.f), q = make_float4(0.f, 0.f, 0.f, 0.f);
    for (; r < NN; r += rstep) {
        float4 v = reinterpret_cast<const float4*>(agg)[r * CH + c];
        s.x += v.x; s.y += v.y; s.z += v.z; s.w += v.w;
        q.x += v.x * v.x; q.y += v.y * v.y; q.z += v.z * v.z; q.w += v.w * v.w;
    }
    atomicAdd(&ssum[c * 4 + 0], s.x); atomicAdd(&ssum[c * 4 + 1], s.y);
    atomicAdd(&ssum[c * 4 + 2], s.z); atomicAdd(&ssum[c * 4 + 3], s.w);
    atomicAdd(&ssq[c * 4 + 0], q.x); atomicAdd(&ssq[c * 4 + 1], q.y);
    atomicAdd(&ssq[c * 4 + 2], q.z); atomicAdd(&ssq[c * 4 + 3], q.w);
    __syncthreads();
    if (threadIdx.x < SP) {
        atomicAdd(&stats[threadIdx.x], ssum[threadIdx.x]);
        atomicAdd(&stats[SP + threadIdx.x], ssq[threadIdx.x]);
    }
}

__global__ void bn_finalize(const float* __restrict__ stats, const float* __restrict__ gamma,
                            const float* __restrict__ beta, float* __restrict__ ab) {
    int f = threadIdx.x;
    if (f >= SP) return;
    float a = 0.f, cc = 0.f;
    if (f < HID) {
        float mu = stats[f] * (1.0f / NN);
        float var = stats[SP + f] * (1.0f / NN) - mu * mu;
        a = gamma[f] * rsqrtf(var + BN_EPS);
        cc = beta[f] - mu * a;
    }
    ab[f] = a;
    ab[SP + f] = cc;
}

__global__ void bn_relu(float* __restrict__ h, const float* __restrict__ ab) {
    int t = blockIdx.x * blockDim.x + threadIdx.x;
    if (t >= NN * CH) return;
    int c = t % CH;
    float4 v = reinterpret_cast<float4*>(h)[t];
    float4 a = reinterpret_cast<const float4*>(ab)[c];
    float4 b = reinterpret_cast<const float4*>(ab + SP)[c];
    v.x = fmaxf(fmaf(v.x, a.x, b.x), 0.f);
    v.y = fmaxf(fmaf(v.y, a.y, b.y), 0.f);
    v.z = fmaxf(fmaf(v.z, a.z, b.z), 0.f);
    v.w = fmaxf(fmaf(v.w, a.w, b.w), 0.f);
    reinterpret_cast<float4*>(h)[t] = v;
}

// ---------------- host ----------------
extern "C" void kernel_launch(void* const* d_in, const int* in_sizes, int n_in,
                              void* d_out, int out_size, void* d_ws, size_t ws_size,
                              hipStream_t stream) {
    const int*   x      = (const int*)d_in[0];
    const int*   ei     = (const int*)d_in[1];
    const float* emb    = (const float*)d_in[2];
    const float* Ws     = (const float*)d_in[3];
    const float* gammas = (const float*)d_in[5];
    const float* betas  = (const float*)d_in[6];
    const float* W_mu   = (const float*)d_in[7];
    const float* b_mu   = (const float*)d_in[8];
    const float* W_ls   = (const float*)d_in[9];
    const float* b_ls   = (const float*)d_in[10];
    float* out = (float*)d_out;

    const int E = in_sizes[1] / 2;
    const int* src = ei;
    const int* dst = ei + E;

    char* ws = (char*)d_ws;
    float* dinv    = (float*)(ws + 0);            // NN floats        (400,000 B)
    float* stats   = (float*)(ws + 400000);       // 160 floats
    float* ab      = (float*)(ws + 400640);       // 160 floats
    int*   hist    = (int*)  (ws + 401408);       // NN ints
    int*   row_ptr = (int*)  (ws + 801408);       // NN+1 ints
    int*   cnt     = (int*)  (ws + 1201536);      // NN ints
    int*   bsum    = (int*)  (ws + 1601536);      // SCAN_NBLK ints
    int*   col     = (int*)  (ws + 1602048);      // NE ints
    float* wgt     = (float*)(ws + 5602048);      // NE floats
    float* hA      = (float*)(ws + 9602048);      // NN*SP floats (32 MB)
    float* hB      = (float*)(ws + 41602048);     // NN*SP floats (32 MB)

    // --- CSR build ---
    hipMemsetAsync(hist, 0, NN * sizeof(int), stream);
    hist_kernel<<<(E + 255) / 256, 256, 0, stream>>>(dst, hist, E);
    dinv_kernel<<<(NN + 255) / 256, 256, 0, stream>>>(hist, dinv, NN);
    scan_pass1<<<SCAN_NBLK, 256, 0, stream>>>(hist, bsum);
    scan_pass2<<<1, 64, 0, stream>>>(bsum, row_ptr, SCAN_NBLK);
    scan_pass3<<<SCAN_NBLK, 256, 0, stream>>>(hist, bsum, row_ptr);
    hipMemsetAsync(cnt, 0, NN * sizeof(int), stream);
    csr_fill<<<(E + 255) / 256, 256, 0, stream>>>(src, dst, row_ptr, cnt, dinv, col, wgt, E);

    // --- h0 = emb[x] ---
    embed_kernel<<<(NN * SP + 255) / 256, 256, 0, stream>>>(x, emb, hA);

    // --- 4 GCN+BN+ReLU layers ---
    for (int layer = 0; layer < 4; ++layer) {
        const float* W = Ws + (size_t)layer * HID * HID;
        gemm_kernel<HID><<<(NN + 12) / 13, 256, 0, stream>>>(hA, W, hB);
        gather75<<<(NN * CH + 255) / 256, 256, 0, stream>>>(row_ptr, col, wgt, hB, dinv, hA);
        hipMemsetAsync(stats, 0, 2 * SP * sizeof(float), stream);
        stats_kernel<<<640, 256, 0, stream>>>(hA, stats);
        bn_finalize<<<1, 128, 0, stream>>>(stats, gammas + layer * HID, betas + layer * HID, ab);
        bn_relu<<<(NN * CH + 255) / 256, 256, 0, stream>>>(hA, ab);
    }

    // --- mu ---
    gemm_kernel<OUTF><<<(NN + 15) / 16, 256, 0, stream>>>(hA, W_mu, hB);
    gather64<<<(NN * CH64 + 255) / 256, 256, 0, stream>>>(row_ptr, col, wgt, hB, dinv, b_mu, out);

    // --- logstd ---
    float* out2 = out + (size_t)NN * OUTF;
    gemm_kernel<OUTF><<<(NN + 15) / 16, 256, 0, stream>>>(hA, W_ls, hB);
    gather64<<<(NN * CH64 + 255) / 256, 256, 0, stream>>>(row_ptr, col, wgt, hB, dinv, b_ls, out2);
}